// Round 11
// baseline (98.635 us; speedup 1.0000x reference)
//
#include <hip/hip_runtime.h>

typedef unsigned long long u64;
typedef unsigned int u32;
typedef unsigned short u16;

#define N_DET 4096
#define NW 64               // 4096 bits = 64 u64 words
#define IOU_TR 0.3f
#define SCORE_TR 0.1f
#define EPS 1e-9f

// ---------------------------------------------------------------------------
// ws layout:
//   rows    : 4096*8 f32   (sorted detection rows)        128 KB
//   soa     : 7*4096 f32   (sorted boxes SoA)             112 KB
//   A       : 64 u64       (bit i = row i nonempty)
//   counter : 16 u32       (last-block counter, padded)
//   EDG     : 4096 records of 8 u16 = [cnt, j0..j6]        64 KB
//   Trm     : 4096*64 u64  (dense-row fallback, rare)       2 MB
// 2 dispatches: k_sort, k_supscan (sup + last-block tail). The tail now
// reads ~13 KB of edge records (not 400 KB of bitmap rows) -> the R7
// fused-tail LLC penalty should collapse.
// ---------------------------------------------------------------------------

__device__ __forceinline__ u64 rl64(u64 v, int l) {
    unsigned lo = __builtin_amdgcn_readlane((unsigned)v, l);
    unsigned hi = __builtin_amdgcn_readlane((unsigned)(v >> 32), l);
    return ((u64)hi << 32) | lo;
}

// K1: stable descending rank sort (R8-exact body) + zero A/counter/sentinel.
__global__ void __launch_bounds__(256) k_sort(const float* __restrict__ res,
                                              float* __restrict__ rows,
                                              float* __restrict__ soa,
                                              u64* __restrict__ A,
                                              u32* __restrict__ counter,
                                              u16* __restrict__ EDG) {
    __shared__ float s[N_DET];
    int tid = threadIdx.x;
    if (blockIdx.x == 0) {
        if (tid < 64) A[tid] = 0ull;
        if (tid == 64) *counter = 0u;
        if (tid == 65) { u64* z = (u64*)(EDG + 4095 * 8); z[0] = 0ull; z[1] = 0ull; }
    }
    for (int j = tid; j < N_DET; j += 256) s[j] = res[j * 8];
    __syncthreads();
    int r = tid >> 4, c = tid & 15;
    int gi = blockIdx.x * 16 + r;
    float sc = s[gi];
    int part = 0;
    int j0 = c * 256;
    for (int j = j0; j < j0 + 256; ++j) {
        float sj = s[j];
        part += (sj > sc) || (sj == sc && j < gi);
    }
    part += __shfl_xor(part, 1, 64);
    part += __shfl_xor(part, 2, 64);
    part += __shfl_xor(part, 4, 64);
    part += __shfl_xor(part, 8, 64);
    if (c == 0) {
        int rank = part;
        float4 a = *(const float4*)(res + gi * 8);
        float4 b = *(const float4*)(res + gi * 8 + 4);
        *(float4*)(rows + rank * 8)     = a;
        *(float4*)(rows + rank * 8 + 4) = b;
        // a = (score, class, cx, cy); b = (cz, dx, dy, dz)
        float cx = a.z, cy = a.w, cz = b.x, dx = b.y, dy = b.z, dz = b.w;
        soa[0 * N_DET + rank] = cx - dx * 0.5f;
        soa[1 * N_DET + rank] = cy - dy * 0.5f;
        soa[2 * N_DET + rank] = cz - dz * 0.5f;
        soa[3 * N_DET + rank] = cx + dx * 0.5f;
        soa[4 * N_DET + rank] = cy + dy * 0.5f;
        soa[5 * N_DET + rank] = cz + dz * 0.5f;
        soa[6 * N_DET + rank] = (dx * dy) * dz;   // np.prod order ((dx*dy)*dz)
    }
}

// Emit one row's compact record (wave-uniform walk; lane 0 stores).
__device__ __forceinline__ void emit_row(int i, u64 rw, u64 orw, int lane,
                                         u16* __restrict__ EDG,
                                         u64* __restrict__ Trm,
                                         u64* __restrict__ A) {
    if (orw) {                                   // wave-uniform
        u64 mm = __ballot(rw != 0ull);           // lanes holding bits
        int tot = 0;
        while (mm) {
            int L = __builtin_ctzll(mm); mm &= mm - 1;
            u64 wb = rl64(rw, L);
            while (wb) {
                int b = __builtin_ctzll(wb); wb &= wb - 1;
                int j = L * 64 + b;
                if (lane == 0 && tot < 7) EDG[(size_t)i * 8 + 1 + tot] = (u16)j;
                ++tot;
            }
        }
        if (lane == 0) EDG[(size_t)i * 8] = (tot <= 7) ? (u16)tot : (u16)0xFFFF;
        if (tot > 7) Trm[(size_t)i * NW + lane] = rw;   // dense fallback row
        if (lane == 0) atomicOr(&A[i >> 6], 1ull << (i & 63));
    }
}

// Edge apply: j_, en_ uniform scalars; per-lane cndmask + andn (~3 VALU).
#define APPLY(JV, EN) { u32 j_ = (JV); u64 bit_ = (EN) ? (1ull << (j_ & 63u)) : 0ull; \
    act &= ~(((u32)lane == (j_ >> 6)) ? bit_ : 0ull); }

// One serial row step; R must be a literal (readlane lane index).
#define ROW(R) { \
    u32 i_ = (u32)s_nlist[g + (R)]; \
    u32 si_ = (u32)__builtin_amdgcn_readfirstlane((int)i_); \
    u64 aw_ = rl64(act, (int)(si_ >> 6)); \
    if ((aw_ >> (si_ & 63u)) & 1ull) { \
        u32 lo0_ = (u32)__builtin_amdgcn_readlane((u32)rec.x, (R)); \
        u32 lo1_ = (u32)__builtin_amdgcn_readlane((u32)(rec.x >> 32), (R)); \
        u32 cnt_ = lo0_ & 0xFFFFu; \
        if (cnt_ == 0xFFFFu) { \
            u64 rowm_ = Trm[(size_t)si_ * NW + lane]; \
            act &= ~rowm_; \
        } else { \
            APPLY(lo0_ >> 16, cnt_ >= 1) \
            APPLY(lo1_ & 0xFFFFu, cnt_ >= 2) \
            if (cnt_ > 2) { \
                u32 hi0_ = (u32)__builtin_amdgcn_readlane((u32)rec.y, (R)); \
                u32 hi1_ = (u32)__builtin_amdgcn_readlane((u32)(rec.y >> 32), (R)); \
                APPLY(lo1_ >> 16, cnt_ >= 3) \
                APPLY(hi0_ & 0xFFFFu, cnt_ >= 4) \
                APPLY(hi0_ >> 16, cnt_ >= 5) \
                APPLY(hi1_ & 0xFFFFu, cnt_ >= 6) \
                APPLY(hi1_ >> 16, cnt_ >= 7) \
            } \
        } \
    } }

#define ROW8(B)  ROW(B+0) ROW(B+1) ROW(B+2) ROW(B+3) ROW(B+4) ROW(B+5) ROW(B+6) ROW(B+7)
#define ROW64    ROW8(0) ROW8(8) ROW8(16) ROW8(24) ROW8(32) ROW8(40) ROW8(48) ROW8(56)

// K2: 2-row-batched mirror-paired sup + last-block tail (edge scan + output).
__global__ void __launch_bounds__(256, 2)
k_supscan(const float* __restrict__ soa, const float* __restrict__ rows,
          u64* __restrict__ Trm, u16* __restrict__ EDG, u64* __restrict__ A,
          u32* __restrict__ counter, float* __restrict__ out) {
    __shared__ u64 s_valid[NW];
    __shared__ u64 s_keep[NW];
    __shared__ u16 s_nlist[4224];
    __shared__ int s_last;
    const int tid = threadIdx.x;
    const int wv = tid >> 6;
    const int lane = tid & 63;

    // ---- sup phase: wave handles rows {i0, i0+1}; blocks 0-255 front,
    // 256-511 mirrored tail rows -> each CU gets one heavy + one light block.
    {
        int p = blockIdx.x * 4 + wv;                 // pair id 0..2047
        int i0 = (p < 1024) ? (2 * p) : (4094 - 2 * (p - 1024));
        int i1 = i0 + 1;
        float alx = soa[0*N_DET+i0], aly = soa[1*N_DET+i0], alz = soa[2*N_DET+i0];
        float ahx = soa[3*N_DET+i0], ahy = soa[4*N_DET+i0], ahz = soa[5*N_DET+i0];
        float av  = soa[6*N_DET+i0];
        float blx = soa[0*N_DET+i1], bly = soa[1*N_DET+i1], blz = soa[2*N_DET+i1];
        float bhx = soa[3*N_DET+i1], bhy = soa[4*N_DET+i1], bhz = soa[5*N_DET+i1];
        float bv  = soa[6*N_DET+i1];
        u64 rw0 = 0, rw1 = 0, or0 = 0, or1 = 0;
        for (int w = (i0 >> 6); w < NW; ++w) {       // straight-line body
            int j = w * 64 + lane;
            float lox = soa[0*N_DET+j], loy = soa[1*N_DET+j], loz = soa[2*N_DET+j];
            float hix = soa[3*N_DET+j], hiy = soa[4*N_DET+j], hiz = soa[5*N_DET+j];
            float vol = soa[6*N_DET+j];
            float ix = fminf(ahx,hix)-fmaxf(alx,lox); ix = fmaxf(ix,0.f);
            float iy = fminf(ahy,hiy)-fmaxf(aly,loy); iy = fmaxf(iy,0.f);
            float iz = fminf(ahz,hiz)-fmaxf(alz,loz); iz = fmaxf(iz,0.f);
            float in0 = (ix * iy) * iz;              // ((x*y)*z) like np.prod
            float un0 = av + vol - in0;              // (vol_i+vol_j)-inter
            float q0 = in0 / (un0 + EPS);            // IEEE div
            u64 m0 = __ballot(q0 > IOU_TR && j > i0);
            float jx = fminf(bhx,hix)-fmaxf(blx,lox); jx = fmaxf(jx,0.f);
            float jy = fminf(bhy,hiy)-fmaxf(bly,loy); jy = fmaxf(jy,0.f);
            float jz = fminf(bhz,hiz)-fmaxf(blz,loz); jz = fmaxf(jz,0.f);
            float in1 = (jx * jy) * jz;
            float un1 = bv + vol - in1;
            float q1 = in1 / (un1 + EPS);
            u64 m1 = __ballot(q1 > IOU_TR && j > i1);
            or0 |= m0; rw0 = (lane == w) ? m0 : rw0;
            or1 |= m1; rw1 = (lane == w) ? m1 : rw1;
        }
        emit_row(i0, rw0, or0, lane, EDG, Trm, A);
        emit_row(i1, rw1, or1, lane, EDG, Trm, A);
    }
    __syncthreads();
    if (tid == 0) {
        __threadfence();                             // release EDG/Trm/A
        u32 old = atomicAdd(counter, 1u);
        s_last = (old == (u32)(gridDim.x - 1));
    }
    __syncthreads();
    if (!s_last) return;
    __threadfence();                                 // acquire all stores

    // ---- tail: valid ballots + edge scan + gated output ----
    for (int w = wv * 16; w < wv * 16 + 16; ++w) {
        float scw = rows[(w * 64 + lane) * 8];
        u64 m = __ballot(scw >= SCORE_TR);
        if (lane == 0) s_valid[w] = m;
    }
    __syncthreads();

    if (wv == 0) {
        u64 act = s_valid[lane];
        u64 avA = A[lane];
        int pc = __popcll(avA);
        int inc = pc;
#pragma unroll
        for (int d = 1; d < 64; d <<= 1) {
            int t = __shfl_up(inc, d, 64);
            if (lane >= d) inc += t;
        }
        int exc = inc - pc;
        int nTotal = __shfl(inc, 63, 64);
        {   // emit this lane's nonempty-row indices (globally sorted)
            u64 m = avA; int o = exc;
            while (m) {
                int k = __builtin_ctzll(m); m &= m - 1;
                s_nlist[o++] = (u16)(lane * 64 + k);
            }
        }
        int padded = (nTotal + 63) & ~63;
        for (int t = nTotal + lane; t < padded + 128 && t < 4224; t += 64)
            s_nlist[t] = (u16)4095;                  // sentinel (record zeroed)
        __threadfence_block();

        for (int g = 0; g < padded; g += 64) {
            u32 myrow = (u32)s_nlist[g + lane];
            ulonglong2 rec = *(const ulonglong2*)(EDG + (size_t)myrow * 8);
            ROW64
        }
        s_keep[lane] = act;                          // final act == keep mask
    }
    __syncthreads();

    // gated output: 256 threads x 16 rows, coalesced
    for (int n = 0; n < 16; ++n) {
        int i = n * 256 + tid;
        bool kp = (s_keep[i >> 6] >> (i & 63)) & 1ull;
        float4 a = kp ? ((const float4*)rows)[i * 2]     : make_float4(0.f, 0.f, 0.f, 0.f);
        float4 b = kp ? ((const float4*)rows)[i * 2 + 1] : make_float4(0.f, 0.f, 0.f, 0.f);
        ((float4*)out)[i * 2]     = a;
        ((float4*)out)[i * 2 + 1] = b;
    }
}

extern "C" void kernel_launch(void* const* d_in, const int* in_sizes, int n_in,
                              void* d_out, int out_size, void* d_ws, size_t ws_size,
                              hipStream_t stream) {
    const float* res = (const float*)d_in[0];
    float* out = (float*)d_out;

    float* rows  = (float*)d_ws;                      // 32768 f32
    float* soa   = rows + N_DET * 8;                  // 28672 f32
    u64*   A     = (u64*)(soa + 7 * N_DET);           // 64 u64
    u32*   counter = (u32*)(A + NW);                  // 16 u32 (padded)
    u16*   EDG   = (u16*)(counter + 16);              // 4096*8 u16 (16B-aligned)
    u64*   Trm   = (u64*)(EDG + N_DET * 8);           // 4096*64 u64

    k_sort   <<<N_DET / 16, 256, 0, stream>>>(res, rows, soa, A, counter, EDG);
    k_supscan<<<512, 256, 0, stream>>>(soa, rows, Trm, EDG, A, counter, out);
}

// Round 12
// 65.462 us; speedup vs baseline: 1.5068x; 1.5068x over previous
//
#include <hip/hip_runtime.h>

typedef unsigned long long u64;
typedef unsigned int u32;
typedef unsigned short u16;

#define N_DET 4096
#define NW 64               // 4096 bits = 64 u64 words
#define IOU_TR 0.3f
#define SCORE_TR 0.1f
#define EPS 1e-9f

// ---------------------------------------------------------------------------
// ws layout (R8 layout):
//   rows : 4096*8 f32  (sorted detection rows)         128 KB
//   soa  : 7*4096 f32  (lox,loy,loz,hix,hiy,hiz,vol)   112 KB
//   A    : 64 u64      (bit i = suppression row i nonempty)
//   keep : 64 u64      (final keep mask)
//   Trm  : 4096*64 u64 row-major bitmatrix; only nonempty rows written.
// 4 dispatches (R8-proven structure): k_sort, k_sup (upper-tri, 2-row
// batched), k_scan (1 block, scalar-mirror chain), k_out.
// LEDGER: R8 59.4 best (sort 4 + sup ~14 + scan ~25 + out 2 + gaps ~14).
//   Regressions to avoid: ov-ballot in sup (R7/R9, +17-30); fused tails
//   (R7/R11); edge-records with in-branch dense loads (R11).
// ---------------------------------------------------------------------------

__device__ __forceinline__ u64 rl64(u64 v, int l) {
    unsigned lo = __builtin_amdgcn_readlane((unsigned)v, l);
    unsigned hi = __builtin_amdgcn_readlane((unsigned)(v >> 32), l);
    return ((u64)hi << 32) | lo;
}

// K1: stable descending rank sort (R8 exact) + zero A.
__global__ void __launch_bounds__(256) k_sort(const float* __restrict__ res,
                                              float* __restrict__ rows,
                                              float* __restrict__ soa,
                                              u64* __restrict__ A) {
    __shared__ float s[N_DET];
    int tid = threadIdx.x;
    if (blockIdx.x == 0 && tid < 64) A[tid] = 0ull;
    for (int j = tid; j < N_DET; j += 256) s[j] = res[j * 8];
    __syncthreads();
    int r = tid >> 4, c = tid & 15;
    int gi = blockIdx.x * 16 + r;
    float sc = s[gi];
    int part = 0;
    int j0 = c * 256;
    for (int j = j0; j < j0 + 256; ++j) {
        float sj = s[j];
        part += (sj > sc) || (sj == sc && j < gi);
    }
    part += __shfl_xor(part, 1, 64);
    part += __shfl_xor(part, 2, 64);
    part += __shfl_xor(part, 4, 64);
    part += __shfl_xor(part, 8, 64);
    if (c == 0) {
        int rank = part;
        float4 a = *(const float4*)(res + gi * 8);
        float4 b = *(const float4*)(res + gi * 8 + 4);
        *(float4*)(rows + rank * 8)     = a;
        *(float4*)(rows + rank * 8 + 4) = b;
        // a = (score, class, cx, cy); b = (cz, dx, dy, dz)
        float cx = a.z, cy = a.w, cz = b.x, dx = b.y, dy = b.z, dz = b.w;
        soa[0 * N_DET + rank] = cx - dx * 0.5f;
        soa[1 * N_DET + rank] = cy - dy * 0.5f;
        soa[2 * N_DET + rank] = cz - dz * 0.5f;
        soa[3 * N_DET + rank] = cx + dx * 0.5f;
        soa[4 * N_DET + rank] = cy + dy * 0.5f;
        soa[5 * N_DET + rank] = cz + dz * 0.5f;
        soa[6 * N_DET + rank] = (dx * dy) * dz;   // np.prod order ((dx*dy)*dz)
    }
}

// K2: suppression rows, upper-triangle, 2-row batched (rows {2p, 2p+1} share
// one straight-line j-loop -> half the soa loads). No per-word branches.
__global__ void k_sup(const float* __restrict__ soa, u64* __restrict__ Trm,
                      u64* __restrict__ A) {
    int lane = threadIdx.x & 63;
    int wave = threadIdx.x >> 6;
    int p = blockIdx.x * 4 + wave;                   // pair id 0..2047
    int i0 = 2 * p, i1 = i0 + 1;
    float alx = soa[0*N_DET+i0], aly = soa[1*N_DET+i0], alz = soa[2*N_DET+i0];
    float ahx = soa[3*N_DET+i0], ahy = soa[4*N_DET+i0], ahz = soa[5*N_DET+i0];
    float av  = soa[6*N_DET+i0];
    float blx = soa[0*N_DET+i1], bly = soa[1*N_DET+i1], blz = soa[2*N_DET+i1];
    float bhx = soa[3*N_DET+i1], bhy = soa[4*N_DET+i1], bhz = soa[5*N_DET+i1];
    float bv  = soa[6*N_DET+i1];
    u64 rw0 = 0, rw1 = 0, or0 = 0, or1 = 0;
    for (int w = (i0 >> 6); w < NW; ++w) {           // i0 even -> same start word
        int j = w * 64 + lane;
        float lox = soa[0*N_DET+j], loy = soa[1*N_DET+j], loz = soa[2*N_DET+j];
        float hix = soa[3*N_DET+j], hiy = soa[4*N_DET+j], hiz = soa[5*N_DET+j];
        float vol = soa[6*N_DET+j];
        float ix = fminf(ahx,hix)-fmaxf(alx,lox); ix = fmaxf(ix,0.f);
        float iy = fminf(ahy,hiy)-fmaxf(aly,loy); iy = fmaxf(iy,0.f);
        float iz = fminf(ahz,hiz)-fmaxf(alz,loz); iz = fmaxf(iz,0.f);
        float in0 = (ix * iy) * iz;                  // ((x*y)*z) like np.prod
        float un0 = av + vol - in0;                  // (vol_i+vol_j)-inter
        float q0 = in0 / (un0 + EPS);                // IEEE div
        u64 m0 = __ballot(q0 > IOU_TR && j > i0);
        float jx = fminf(bhx,hix)-fmaxf(blx,lox); jx = fmaxf(jx,0.f);
        float jy = fminf(bhy,hiy)-fmaxf(bly,loy); jy = fmaxf(jy,0.f);
        float jz = fminf(bhz,hiz)-fmaxf(blz,loz); jz = fmaxf(jz,0.f);
        float in1 = (jx * jy) * jz;
        float un1 = bv + vol - in1;
        float q1 = in1 / (un1 + EPS);
        u64 m1 = __ballot(q1 > IOU_TR && j > i1);
        or0 |= m0; rw0 = (lane == w) ? m0 : rw0;
        or1 |= m1; rw1 = (lane == w) ? m1 : rw1;
    }
    if (or0) {
        Trm[(size_t)i0 * NW + lane] = rw0;
        if (lane == 0) atomicOr(&A[i0 >> 6], 1ull << (i0 & 63));
    }
    if (or1) {
        Trm[(size_t)i1 * NW + lane] = rw1;
        if (lane == 0) atomicOr(&A[i1 >> 6], 1ull << (i1 & 63));
    }
}

// K3: sparse greedy scan with SCALAR current-word mirror.
// Per row: idx readlane + SALU bit test on s_cur (scalar chain only);
// the vector apply (act &= ~P) is off-chain; s_cur updated via one
// readlane64 of the in-register row slot. act readlane only at word
// boundaries (~65 times total). Loads stay 32-row chain-independent (R8).
#define FIDX(V, GB) { V = (u32)s_nlist[(GB) + (lane & 15)]; }

#define IS1(V, P, S) { u32 si_ = (u32)__builtin_amdgcn_readlane((V), (S)); \
    P##S = Trm[(size_t)si_ * NW + lane]; }

#define IS16(V, P) IS1(V,P,0) IS1(V,P,1) IS1(V,P,2) IS1(V,P,3)   \
    IS1(V,P,4) IS1(V,P,5) IS1(V,P,6) IS1(V,P,7)                  \
    IS1(V,P,8) IS1(V,P,9) IS1(V,P,10) IS1(V,P,11)                \
    IS1(V,P,12) IS1(V,P,13) IS1(V,P,14) IS1(V,P,15)

#define PR1(V, P, S) { \
    u32 si_ = (u32)__builtin_amdgcn_readlane((V), (S)); \
    u32 w_ = si_ >> 6; \
    if (w_ != s_w) {                       /* uniform: word advance */ \
        s_cur = rl64(act, (int)w_); s_w = w_; } \
    if (si_ != 4095u && ((s_cur >> (si_ & 63u)) & 1ull)) {  /* uniform */ \
        act &= ~P##S;                      /* vector apply, off-chain */ \
        s_cur &= ~rl64(P##S, (int)w_);     /* scalar mirror update */ } }

#define PR16(V, P) PR1(V,P,0) PR1(V,P,1) PR1(V,P,2) PR1(V,P,3)   \
    PR1(V,P,4) PR1(V,P,5) PR1(V,P,6) PR1(V,P,7)                  \
    PR1(V,P,8) PR1(V,P,9) PR1(V,P,10) PR1(V,P,11)                \
    PR1(V,P,12) PR1(V,P,13) PR1(V,P,14) PR1(V,P,15)

__global__ void __launch_bounds__(256, 1)
k_scan(const u64* __restrict__ Trm, const u64* __restrict__ A,
       const float* __restrict__ rows, u64* __restrict__ keep) {
    __shared__ u64 s_valid[NW];
    __shared__ u16 s_nlist[4224];
    const int tid = threadIdx.x;
    const int wv = tid >> 6;
    const int lane = tid & 63;

    for (int w = wv * 16; w < wv * 16 + 16; ++w) {
        float scw = rows[(w * 64 + lane) * 8];
        u64 m = __ballot(scw >= SCORE_TR);
        if (lane == 0) s_valid[w] = m;
    }
    __syncthreads();
    if (wv != 0) return;

    u64 act = s_valid[lane];
    u64 avA = A[lane];
    int pc = __popcll(avA);
    int inc = pc;
#pragma unroll
    for (int d = 1; d < 64; d <<= 1) {
        int t = __shfl_up(inc, d, 64);
        if (lane >= d) inc += t;
    }
    int exc = inc - pc;
    int nTotal = __shfl(inc, 63, 64);
    {   // emit this lane's nonempty-row indices (globally sorted)
        u64 m = avA; int o = exc;
        while (m) {
            int k = __builtin_ctzll(m); m &= m - 1;
            s_nlist[o++] = (u16)(lane * 64 + k);
        }
    }
    int padded = (nTotal + 63) & ~63;
    for (int t = nTotal + lane; t < padded + 128; t += 64)
        s_nlist[t] = (u16)4095;            // sentinel (skipped in PR1)
    __threadfence_block();                 // wave-local LDS ordering

    if (padded > 0) {
        u64 pa0,pa1,pa2,pa3,pa4,pa5,pa6,pa7,
            pa8,pa9,pa10,pa11,pa12,pa13,pa14,pa15;
        u64 pb0,pb1,pb2,pb3,pb4,pb5,pb6,pb7,
            pb8,pb9,pb10,pb11,pb12,pb13,pb14,pb15;
        u32 iA0, iA1, iB0, iB1;
        u32 s_w = 0xFFFFFFFFu;             // force advance on first row
        u64 s_cur = 0ull;
        FIDX(iA0, 0)  IS16(iA0, pa)
        FIDX(iB0, 16) IS16(iB0, pb)
        int g = 0;
        while (g < padded) {
            FIDX(iA1, g + 32)
            PR16(iA0, pa)                  // rows g..g+15
            IS16(iA1, pa)                  // issue g+32
            FIDX(iB1, g + 48)
            PR16(iB0, pb)                  // rows g+16..g+31
            IS16(iB1, pb)                  // issue g+48
            g += 32;
            if (g >= padded) break;
            FIDX(iA0, g + 32)
            PR16(iA1, pa)
            IS16(iA0, pa)
            FIDX(iB0, g + 48)
            PR16(iB1, pb)
            IS16(iB0, pb)
            g += 32;
        }
    }
    keep[lane] = act;                      // final act == keep mask
}

// K4: gated output, 16 blocks x 256 threads, coalesced (R8 exact).
__global__ void k_out(const float* __restrict__ rows,
                      const u64* __restrict__ keep,
                      float* __restrict__ out) {
    int i = blockIdx.x * 256 + threadIdx.x;
    bool kp = (keep[i >> 6] >> (i & 63)) & 1ull;
    float4 a = kp ? ((const float4*)rows)[i * 2]     : make_float4(0.f, 0.f, 0.f, 0.f);
    float4 b = kp ? ((const float4*)rows)[i * 2 + 1] : make_float4(0.f, 0.f, 0.f, 0.f);
    ((float4*)out)[i * 2]     = a;
    ((float4*)out)[i * 2 + 1] = b;
}

extern "C" void kernel_launch(void* const* d_in, const int* in_sizes, int n_in,
                              void* d_out, int out_size, void* d_ws, size_t ws_size,
                              hipStream_t stream) {
    const float* res = (const float*)d_in[0];
    float* out = (float*)d_out;

    float* rows = (float*)d_ws;                       // 32768 f32
    float* soa  = rows + N_DET * 8;                   // 28672 f32
    u64* A      = (u64*)(soa + 7 * N_DET);            // 64 u64
    u64* keep   = A + NW;                             // 64 u64
    u64* Trm    = keep + NW;                          // 4096*64 u64 (row-major)

    k_sort<<<N_DET / 16, 256, 0, stream>>>(res, rows, soa, A);
    k_sup <<<512, 256, 0, stream>>>(soa, Trm, A);
    k_scan<<<1, 256, 0, stream>>>(Trm, A, rows, keep);
    k_out <<<16, 256, 0, stream>>>(rows, keep, out);
}